// Round 8
// baseline (527.659 us; speedup 1.0000x reference)
//
#include <hip/hip_runtime.h>
#include <hip/hip_bf16.h>
#include <stdint.h>

#define E_EDGES 80000
#define N_NODES 10000
#define HD      64
#define DDIST   128
#define NCOEF   49
#define W3OUT   224   // M0(7) * C_SPH(32)
#define WROW    2401  // 49*49
#define NELEM   90

// Compile-time destination LUT: rel (0..2400) -> row*8+slot, or -1 if the
// column rel%49 is not one of {0,2,6,12,20,30,42}.
struct Lut { short v[WROW]; };
static constexpr Lut make_lut() {
    Lut L{};
    for (int rel = 0; rel < WROW; ++rel) {
        const int row = rel / 49;
        const int col = rel - row * 49;
        int slot = -1;
        const int cols[7] = {0, 2, 6, 12, 20, 30, 42};
        for (int s = 0; s < 7; ++s) if (cols[s] == col) slot = s;
        L.v[rel] = (slot >= 0) ? (short)(row * 8 + slot) : (short)-1;
    }
    return L;
}
__device__ const Lut d_lut = make_lut();

struct F8 { float v[8]; };

// ---------------------------------------------------------------------------
// k_pre: fold embedding tables through W1 slices; also zero cnt[].
// grid = 157 blocks x 64 (covers N_NODES zeroing; first 90 build tables).
// ---------------------------------------------------------------------------
__global__ __launch_bounds__(64) void k_pre(
    const float* __restrict__ semb, const float* __restrict__ temb,
    const float* __restrict__ W1,
    float* __restrict__ sW1, float* __restrict__ tW1, int* __restrict__ cnt)
{
    const int lane = threadIdx.x;
    const int zi = blockIdx.x * 64 + lane;
    if (zi < N_NODES) cnt[zi] = 0;
    const int z = blockIdx.x;
    if (z < NELEM) {
        float sa = 0.f, ta = 0.f;
        #pragma unroll 4
        for (int k = 0; k < HD; k++) {
            sa = fmaf(semb[z * HD + k], W1[(128 + k) * HD + lane], sa);
            ta = fmaf(temb[z * HD + k], W1[(192 + k) * HD + lane], ta);
        }
        sW1[z * HD + lane] = sa;
        tW1[z * HD + lane] = ta;
    }
}

// ---------------------------------------------------------------------------
// CSR build (frozen)
// ---------------------------------------------------------------------------
__global__ void k_count(const int* __restrict__ ei, int* __restrict__ cnt) {
    const int e = blockIdx.x * 256 + threadIdx.x;
    if (e < E_EDGES) atomicAdd(&cnt[ei[E_EDGES + e]], 1);
}

__global__ __launch_bounds__(1024) void k_scan(const int* __restrict__ cnt,
                                               int* __restrict__ offs,
                                               int* __restrict__ cursor) {
    __shared__ int wsum[16];
    __shared__ int carry_s;
    const int tid  = threadIdx.x;
    const int lane = tid & 63;
    const int wid  = tid >> 6;
    if (tid == 0) carry_s = 0;
    __syncthreads();
    for (int base = 0; base < N_NODES; base += 1024) {
        const int idx = base + tid;
        const int v = (idx < N_NODES) ? cnt[idx] : 0;
        int s = v;
        #pragma unroll
        for (int off = 1; off < 64; off <<= 1) {
            const int t = __shfl_up(s, off, 64);
            if (lane >= off) s += t;
        }
        if (lane == 63) wsum[wid] = s;
        __syncthreads();
        if (wid == 0) {
            const int t = (lane < 16) ? wsum[lane] : 0;
            int ss = t;
            #pragma unroll
            for (int off = 1; off < 16; off <<= 1) {
                const int u = __shfl_up(ss, off, 64);
                if (lane >= off) ss += u;
            }
            if (lane < 16) wsum[lane] = ss - t;
        }
        __syncthreads();
        const int carry = carry_s;
        const int excl = carry + wsum[wid] + s - v;
        if (idx < N_NODES) { offs[idx] = excl; cursor[idx] = excl; }
        __syncthreads();
        if (tid == 1023) carry_s = carry + wsum[15] + s;
    }
    __syncthreads();
    if (tid == 0) offs[N_NODES] = carry_s;
}

__global__ void k_scatter(const int* __restrict__ ei, int* __restrict__ cursor,
                          int* __restrict__ eids) {
    const int e = blockIdx.x * 256 + threadIdx.x;
    if (e < E_EDGES) {
        const int pos = atomicAdd(&cursor[ei[E_EDGES + e]], 1);
        eids[pos] = e;
    }
}

// ---------------------------------------------------------------------------
// k_fused (round 8): block per node; per chunk of <=8 edges, the 4 waves run
// the MLP (2 edges/wave) into LDS ylc[8][224] (y3 never touches HBM), then
// the round-6 wigner-stream pipeline consumes them.
// ---------------------------------------------------------------------------
__global__ __launch_bounds__(256, 4) void k_fused(
    const int* __restrict__ an, const int* __restrict__ ei,
    const float* __restrict__ ed,
    const float* __restrict__ sW1, const float* __restrict__ tW1,
    const float* __restrict__ W1, const float* __restrict__ b1,
    const float* __restrict__ g1, const float* __restrict__ be1,
    const float* __restrict__ W2, const float* __restrict__ b2,
    const float* __restrict__ g2, const float* __restrict__ be2,
    const float* __restrict__ W3, const float* __restrict__ b3,
    const float* __restrict__ wig,
    const int* __restrict__ offs, const int* __restrict__ eids,
    float* __restrict__ out)
{
    __shared__ __align__(16) float wl[NCOEF * 8];     // wigner cols [i][slot]
    __shared__ __align__(16) float ylc[8][W3OUT];     // chunk y3 rows
    __shared__ float hT[4][HD * 2];
    __shared__ float h2T[4][HD * 2];
    __shared__ short lut_s[WROW + 1];

    const int n    = blockIdx.x;
    const int tid  = threadIdx.x;
    const int wave = tid >> 6;
    const int lane = tid & 63;
    const int c    = tid & 31;
    const int rr   = tid >> 5;
    const int beg  = offs[n];
    const int end  = offs[n + 1];

    // stage LUT (first consumer is KOUT_COMMIT, after a barrier)
    {
        const int* __restrict__ lsrc = (const int*)d_lut.v;
        int* __restrict__ ldst = (int*)lut_s;
        for (int j = tid; j < 1200; j += 256) ldst[j] = lsrc[j];
        if (tid == 0) lut_s[2400] = d_lut.v[2400];
    }

    float acc7[7];
    #pragma unroll
    for (int r = 0; r < 7; r++) acc7[r] = 0.f;

    const float4* __restrict__ wig4 = (const float4*)wig;
    const size_t NF4_TOTAL = ((size_t)E_EDGES * WROW) >> 2;
    float4 v0, v1, v2;
    int d = 0;

    #define KOUT_ISSUE(E) do {                                              \
        const size_t rs = (size_t)(E) * WROW;                               \
        const size_t B  = rs >> 2;                                          \
        d = (int)(rs & 3);                                                  \
        v0 = make_float4(0.f,0.f,0.f,0.f); v1 = v0; v2 = v0;                \
        const size_t j0 = B + tid, j1 = j0 + 256, j2 = j0 + 512;            \
        if (j0 < NF4_TOTAL)               v0 = wig4[j0];                    \
        if (j1 < NF4_TOTAL)               v1 = wig4[j1];                    \
        if (tid < 89 && j2 < NF4_TOTAL)   v2 = wig4[j2];                    \
    } while (0)

    #define KOUT_UNPACK(VV, R) do {                                         \
        const float xx[4] = {(VV).x, (VV).y, (VV).z, (VV).w};               \
        _Pragma("unroll")                                                   \
        for (int k = 0; k < 4; k++) {                                       \
            const int rel = 1024 * (R) + 4 * tid + k - d;                   \
            if (rel >= 0 && rel < WROW) {                                   \
                const int idx = lut_s[rel];                                 \
                if (idx >= 0) wl[idx] = xx[k];                              \
            }                                                               \
        }                                                                   \
    } while (0)

    #define KOUT_COMMIT() do {                                              \
        KOUT_UNPACK(v0, 0); KOUT_UNPACK(v1, 1); KOUT_UNPACK(v2, 2);         \
    } while (0)

    const int nchunk = (end - beg + 7) >> 3;
    float* __restrict__ hw  = hT[wave];
    float* __restrict__ h2w = h2T[wave];

    for (int ck = 0; ck < nchunk; ck++) {
        const int cbase = beg + ck * 8;
        const int nj = min(8, end - cbase);

        // issue wigner loads for edge(ck,0) -- latency hides under the MLP
        KOUT_ISSUE(eids[cbase]);

        // ---------------- MLP: 2 edges per wave into ylc -------------------
        {
            const int sA = cbase + wave * 2;
            const int sB = sA + 1;
            const int eA = __builtin_amdgcn_readfirstlane(eids[sA < end ? sA : beg]);
            const int eB = __builtin_amdgcn_readfirstlane(eids[sB < end ? sB : beg]);

            float acc[2];
            {
                const int zsA = an[ei[eA]], ztA = an[ei[E_EDGES + eA]];
                const int zsB = an[ei[eB]], ztB = an[ei[E_EDGES + eB]];
                acc[0] = sW1[zsA * HD + lane] + tW1[ztA * HD + lane];
                acc[1] = sW1[zsB * HD + lane] + tW1[ztB * HD + lane];
            }
            #pragma unroll 2
            for (int kc = 0; kc < 16; kc++) {
                float w[8];
                #pragma unroll
                for (int j = 0; j < 8; j++) w[j] = W1[(kc * 8 + j) * HD + lane];
                const F8 xA = *(const F8*)(ed + (size_t)eA * DDIST + kc * 8);
                const F8 xB = *(const F8*)(ed + (size_t)eB * DDIST + kc * 8);
                #pragma unroll
                for (int j = 0; j < 8; j++) {
                    acc[0] = fmaf(w[j], xA.v[j], acc[0]);
                    acc[1] = fmaf(w[j], xB.v[j], acc[1]);
                }
            }
            // LN + silu (1)
            {
                const float bb = b1[lane], gg = g1[lane], be = be1[lane];
                #pragma unroll
                for (int ep = 0; ep < 2; ep++) {
                    float h = acc[ep] + bb;
                    float s = h, s2 = h * h;
                    #pragma unroll
                    for (int off = 32; off > 0; off >>= 1) {
                        s  += __shfl_xor(s,  off, 64);
                        s2 += __shfl_xor(s2, off, 64);
                    }
                    const float mu  = s * (1.f / 64.f);
                    const float var = fmaxf(s2 * (1.f / 64.f) - mu * mu, 0.f);
                    const float t   = (h - mu) * rsqrtf(var + 1e-5f) * gg + be;
                    hw[lane * 2 + ep] = t / (1.f + expf(-t));
                }
            }
            // layer 2 (hT is wave-private; same-wave LDS RAW handled by lgkmcnt)
            float acc2[2] = {0.f, 0.f};
            #pragma unroll 4
            for (int k = 0; k < HD; k++) {
                const float w = W2[k * HD + lane];
                const float2 xa = *(const float2*)(hw + k * 2);
                acc2[0] = fmaf(w, xa.x, acc2[0]);
                acc2[1] = fmaf(w, xa.y, acc2[1]);
            }
            {
                const float bb = b2[lane], gg = g2[lane], be = be2[lane];
                #pragma unroll
                for (int ep = 0; ep < 2; ep++) {
                    float h = acc2[ep] + bb;
                    float s = h, s2 = h * h;
                    #pragma unroll
                    for (int off = 32; off > 0; off >>= 1) {
                        s  += __shfl_xor(s,  off, 64);
                        s2 += __shfl_xor(s2, off, 64);
                    }
                    const float mu  = s * (1.f / 64.f);
                    const float var = fmaxf(s2 * (1.f / 64.f) - mu * mu, 0.f);
                    const float t   = (h - mu) * rsqrtf(var + 1e-5f) * gg + be;
                    h2w[lane * 2 + ep] = t / (1.f + expf(-t));
                }
            }
            // layer 3: 4 chunks fused
            float a2[4][2];
            #pragma unroll
            for (int ch = 0; ch < 4; ch++) { a2[ch][0] = 0.f; a2[ch][1] = 0.f; }
            #pragma unroll 2
            for (int k = 0; k < HD; k++) {
                const float w0 = W3[k * W3OUT + lane];
                const float w1 = W3[k * W3OUT + 64 + lane];
                const float w2 = W3[k * W3OUT + 128 + lane];
                const float w3 = (lane < 32) ? W3[k * W3OUT + 192 + lane] : 0.f;
                const float2 xa = *(const float2*)(h2w + k * 2);
                a2[0][0] = fmaf(w0, xa.x, a2[0][0]); a2[0][1] = fmaf(w0, xa.y, a2[0][1]);
                a2[1][0] = fmaf(w1, xa.x, a2[1][0]); a2[1][1] = fmaf(w1, xa.y, a2[1][1]);
                a2[2][0] = fmaf(w2, xa.x, a2[2][0]); a2[2][1] = fmaf(w2, xa.y, a2[2][1]);
                a2[3][0] = fmaf(w3, xa.x, a2[3][0]); a2[3][1] = fmaf(w3, xa.y, a2[3][1]);
            }
            #pragma unroll
            for (int ch = 0; ch < 4; ch++) {
                const int chn = ch * 64 + lane;
                if (ch < 3 || lane < 32) {
                    const float bb3 = b3[chn];
                    ylc[wave * 2 + 0][chn] = (a2[ch][0] + bb3) * (1.0f / 5.862f);
                    ylc[wave * 2 + 1][chn] = (a2[ch][1] + bb3) * (1.0f / 5.862f);
                }
            }
        }

        __syncthreads();          // ylc visible; LUT staged; prior wl readers done
        KOUT_COMMIT();            // wl for edge(ck,0)

        for (int j = 0; j < nj; j++) {
            __syncthreads();                       // wl staged visible
            if (j + 1 < nj) KOUT_ISSUE(eids[cbase + j + 1]);
            float yr[7];
            #pragma unroll
            for (int l = 0; l < 7; l++) yr[l] = ylc[j][l * 32 + c];
            #pragma unroll
            for (int r = 0; r < 7; r++) {
                const int i = r * 8 + rr;
                if (i < NCOEF) {
                    const float4 wa = *(const float4*)(wl + i * 8);
                    const float4 wb = *(const float4*)(wl + i * 8 + 4);
                    acc7[r] += wa.x * yr[0] + wa.y * yr[1] + wa.z * yr[2] + wa.w * yr[3]
                             + wb.x * yr[4] + wb.y * yr[5] + wb.z * yr[6];
                }
            }
            __syncthreads();                       // wl readers done
            if (j + 1 < nj) KOUT_COMMIT();
        }
    }

    #pragma unroll
    for (int r = 0; r < 7; r++) {
        const int i = r * 8 + rr;
        if (i < NCOEF) out[(size_t)n * (NCOEF * 32) + i * 32 + c] = acc7[r];
    }
}

// ---------------------------------------------------------------------------
extern "C" void kernel_launch(void* const* d_in, const int* in_sizes, int n_in,
                              void* d_out, int out_size, void* d_ws, size_t ws_size,
                              hipStream_t stream)
{
    const int*   an   = (const int*)  d_in[0];
    const int*   ei   = (const int*)  d_in[1];
    const float* ed   = (const float*)d_in[2];
    const float* wig  = (const float*)d_in[3];
    const float* semb = (const float*)d_in[4];
    const float* temb = (const float*)d_in[5];
    const float* W1   = (const float*)d_in[6];
    const float* b1   = (const float*)d_in[7];
    const float* g1   = (const float*)d_in[8];
    const float* be1  = (const float*)d_in[9];
    const float* W2   = (const float*)d_in[10];
    const float* b2   = (const float*)d_in[11];
    const float* g2   = (const float*)d_in[12];
    const float* be2  = (const float*)d_in[13];
    const float* W3   = (const float*)d_in[14];
    const float* b3   = (const float*)d_in[15];
    float* out = (float*)d_out;

    char* ws = (char*)d_ws;
    int*   cnt    = (int*)ws;
    int*   offs   = cnt + N_NODES;
    int*   cursor = offs + N_NODES + 1;
    int*   eids   = cursor + N_NODES;
    float* sW1    = (float*)(eids + E_EDGES);
    float* tW1    = sW1 + NELEM * HD;
    const size_t need =
        sizeof(int) * ((size_t)N_NODES + (N_NODES + 1) + N_NODES + E_EDGES) +
        sizeof(float) * (2 * NELEM * HD);
    if (ws_size < need) return;

    k_pre<<<(N_NODES + 63) / 64, 64, 0, stream>>>(semb, temb, W1, sW1, tW1, cnt);
    k_count<<<(E_EDGES + 255) / 256, 256, 0, stream>>>(ei, cnt);
    k_scan<<<1, 1024, 0, stream>>>(cnt, offs, cursor);
    k_scatter<<<(E_EDGES + 255) / 256, 256, 0, stream>>>(ei, cursor, eids);
    k_fused<<<N_NODES, 256, 0, stream>>>(an, ei, ed, sW1, tW1,
                                         W1, b1, g1, be1,
                                         W2, b2, g2, be2, W3, b3,
                                         wig, offs, eids, out);
}